// Round 7
// baseline (425.157 us; speedup 1.0000x reference)
//
#include <hip/hip_runtime.h>

#define NNODES 50000
#define NEDGES 600000
#define HID 128
#define NLAYERS 4
#define NOUT 8
#define BN_EPS 1e-5f
#define NBLK 196  // ceil(NNODES/256)

typedef short short8 __attribute__((ext_vector_type(8)));
typedef float f32x4 __attribute__((ext_vector_type(4)));

__device__ inline unsigned short f2bf(float f) {
  unsigned u = __float_as_uint(f);
  unsigned r = ((u >> 16) & 1u) + 0x7fffu;
  return (unsigned short)((u + r) >> 16);
}
__device__ inline float bflo(unsigned w) { return __uint_as_float(w << 16); }
__device__ inline float bfhi(unsigned w) { return __uint_as_float(w & 0xffff0000u); }

// ---------------- utility kernels ----------------

__global__ void zero_stats_k(float* stats) {
  for (int j = threadIdx.x; j < 1024; j += 256) stats[j] = 0.f;
}

// Detect whether edge_index arrived as int64 (odd int32 words all zero) or int32.
__global__ void detect64_k(const int* __restrict__ ei, int* __restrict__ flag) {
  __shared__ int anynz;
  if (threadIdx.x == 0) anynz = 0;
  __syncthreads();
  int acc = 0;
  for (int i = threadIdx.x; i < 4096; i += 256) {
    int p = i * 146;
    acc |= ei[2 * p + 1];
  }
  if (acc != 0) anynz = 1;
  __syncthreads();
  if (threadIdx.x == 0) *flag = (anynz == 0) ? 1 : 0;  // 1 => int64 layout
}

// fp32 -> bf16 convert (for the input x gather table)
__global__ void cvt_bf_k(const float* __restrict__ src, unsigned short* __restrict__ dst,
                         int n4) {
  int i = blockIdx.x * 256 + threadIdx.x;
  if (i >= n4) return;
  float4 v = ((const float4*)src)[i];
  ushort4 o;
  o.x = f2bf(v.x);
  o.y = f2bf(v.y);
  o.z = f2bf(v.z);
  o.w = f2bf(v.w);
  ((ushort4*)dst)[i] = o;
}

// ---------------- CSR build ----------------

__global__ void zero_deg_k(int* __restrict__ deg) {
  int i = blockIdx.x * 256 + threadIdx.x;
  if (i < NNODES + 1) deg[i] = 0;
}

__global__ void hist_k(const int* __restrict__ ei, const int* __restrict__ flag,
                       int* __restrict__ deg) {
  int e = blockIdx.x * 256 + threadIdx.x;
  if (e >= NEDGES) return;
  int d = (*flag) ? ei[2 * NEDGES + 2 * e] : ei[NEDGES + e];
  atomicAdd(&deg[d], 1);
}

// Parallel scan, phase A: per-block (256-chunk) sums.
__global__ void blocksum_k(const int* __restrict__ deg, int* __restrict__ bsum) {
  int t = threadIdx.x;
  int i = blockIdx.x * 256 + t;
  __shared__ int sh[256];
  sh[t] = (i < NNODES) ? deg[i] : 0;
  __syncthreads();
  for (int s = 128; s > 0; s >>= 1) {
    if (t < s) sh[t] += sh[t + s];
    __syncthreads();
  }
  if (t == 0) bsum[blockIdx.x] = sh[0];
}

// Phase B: single-block exclusive scan of the NBLK block sums.
__global__ void scanb_k(const int* __restrict__ bsum, int* __restrict__ boff) {
  __shared__ int sh[256];
  int t = threadIdx.x;
  sh[t] = (t < NBLK) ? bsum[t] : 0;
  __syncthreads();
  for (int d = 1; d < 256; d <<= 1) {
    int v = (t >= d) ? sh[t - d] : 0;
    __syncthreads();
    sh[t] += v;
    __syncthreads();
  }
  if (t < NBLK) boff[t] = (t == 0) ? 0 : sh[t - 1];
}

// Phase C: per-block exclusive scan + block offset -> off/cursor.
__global__ void writeoff_k(const int* __restrict__ deg, const int* __restrict__ boff,
                           int* __restrict__ off, int* __restrict__ cursor) {
  int t = threadIdx.x;
  int i = blockIdx.x * 256 + t;
  __shared__ int sh[256];
  int v = (i < NNODES) ? deg[i] : 0;
  sh[t] = v;
  __syncthreads();
  for (int d = 1; d < 256; d <<= 1) {
    int u = (t >= d) ? sh[t - d] : 0;
    __syncthreads();
    sh[t] += u;
    __syncthreads();
  }
  int excl = boff[blockIdx.x] + sh[t] - v;
  if (i < NNODES) {
    off[i] = excl;
    cursor[i] = excl;
  }
  if (i == NNODES - 1) off[NNODES] = excl + v;
}

__global__ void fill_k(const int* __restrict__ ei, const int* __restrict__ flag,
                       int* __restrict__ cursor, int* __restrict__ srcs) {
  int e = blockIdx.x * 256 + threadIdx.x;
  if (e >= NEDGES) return;
  int s, d;
  if (*flag) {
    s = ei[2 * e];
    d = ei[2 * NEDGES + 2 * e];
  } else {
    s = ei[e];
    d = ei[NEDGES + e];
  }
  int pos = atomicAdd(&cursor[d], 1);
  srcs[pos] = s;
}

// ---------------- fused gather-aggregate (bf16 table -> bf16 out) ----------------
__global__ void gather_agg_k(const unsigned short* __restrict__ X,
                             const int* __restrict__ off, const int* __restrict__ srcs,
                             unsigned short* __restrict__ T) {
  int gid = blockIdx.x * 256 + threadIdx.x;
  int node = gid >> 5;
  if (node >= NNODES) return;
  int lane = gid & 31;
  int a = off[node], b = off[node + 1];
  const uint2* Xv = (const uint2*)X;
  uint2 w = Xv[(size_t)node * 32 + lane];
  float a0 = bflo(w.x), a1 = bfhi(w.x), a2 = bflo(w.y), a3 = bfhi(w.y);
  for (int base = a; base < b; base += 32) {
    int cnt = b - base;
    if (cnt > 32) cnt = 32;
    int idx = (lane < cnt) ? srcs[base + lane] : 0;
#pragma unroll 8
    for (int i = 0; i < cnt; ++i) {
      int s = __shfl(idx, i, 32);
      uint2 v = Xv[(size_t)s * 32 + lane];
      a0 += bflo(v.x);
      a1 += bfhi(v.x);
      a2 += bflo(v.y);
      a3 += bfhi(v.y);
    }
  }
  uint2 o;
  o.x = (unsigned)f2bf(a0) | ((unsigned)f2bf(a1) << 16);
  o.y = (unsigned)f2bf(a2) | ((unsigned)f2bf(a3) << 16);
  ((uint2*)T)[(size_t)node * 32 + lane] = o;
}

// ---------------- weight pre-pack into MFMA B-fragment layout ----------------
__global__ void packW_k(const float* __restrict__ W1, const float* __restrict__ W2,
                        const float* __restrict__ L1, unsigned short* __restrict__ P) {
  int t = blockIdx.x * 256 + threadIdx.x;
  if (t >= 48 * 512) return;
  int gk = t >> 9;
  int nt = (t >> 6) & 7;
  int lane = t & 63;
  const float* src;
  int kbase;
  if (gk < 16) {
    src = W1 + (gk >> 2) * 16384;
    kbase = (gk & 3) * 32;
  } else if (gk < 32) {
    src = W2 + ((gk - 16) >> 2) * 16384;
    kbase = ((gk - 16) & 3) * 32;
  } else {
    src = L1;
    kbase = (gk - 32) * 32;
  }
  int n = nt * 16 + (lane & 15);
  int k0 = kbase + (lane >> 4) * 8;
  unsigned short* dst = P + (size_t)t * 8;
#pragma unroll
  for (int j = 0; j < 8; ++j) dst[j] = f2bf(src[(size_t)(k0 + j) * HID + n]);
}

// ---------------- fused MLP: H = relu(relu(A@W1+b1)@W2+b2), + BN stats ----------------
// B matrices staged in LDS (coalesced block copy), fragments via ds_read_b128.
__global__ __launch_bounds__(256, 3) void mlp_k(const unsigned short* __restrict__ A,
                                                const unsigned short* __restrict__ P1,
                                                const float* __restrict__ bias1,
                                                const unsigned short* __restrict__ P2,
                                                const float* __restrict__ bias2,
                                                float* __restrict__ H, int M,
                                                float* __restrict__ gsum,
                                                float* __restrict__ gsq) {
  __shared__ unsigned short sB[16384];        // one 128x128 bf16 B-fragment slab (32 KB)
  __shared__ unsigned short sA[4][16 * 136];  // per-wave stage1->stage2 slab
  __shared__ float sSum[128], sSq[128];
  int tid = threadIdx.x;
  if (tid < 128) {
    sSum[tid] = 0.f;
    sSq[tid] = 0.f;
  }
  int lane = tid & 63, w = tid >> 6;
  int rb = blockIdx.x * 64 + w * 16;
  int r = rb + (lane & 15);
  if (r > M - 1) r = M - 1;
  int hi = lane >> 4, c = lane & 15;
  int koff = hi * 8;

  // stage B1 into LDS (coalesced, pipelined)
  {
    const short8* src = (const short8*)P1;
    short8* dst = (short8*)sB;
#pragma unroll
    for (int i = 0; i < 8; ++i) dst[tid + i * 256] = src[tid + i * 256];
  }
  // hoist A-row loads (independent of LDS)
  short8 a_[4];
  const unsigned short* Ar = A + (size_t)r * HID + koff;
#pragma unroll
  for (int ks = 0; ks < 4; ++ks) a_[ks] = *(const short8*)(Ar + ks * 32);
  __syncthreads();

  const short8* sBv = (const short8*)sB;
  f32x4 acc[8];
#pragma unroll
  for (int nt = 0; nt < 8; ++nt) acc[nt] = (f32x4){0.f, 0.f, 0.f, 0.f};
#pragma unroll
  for (int ks = 0; ks < 4; ++ks) {
#pragma unroll
    for (int nt = 0; nt < 8; ++nt)
      acc[nt] = __builtin_amdgcn_mfma_f32_16x16x32_bf16(a_[ks], sBv[ks * 512 + nt * 64 + lane],
                                                        acc[nt], 0, 0, 0);
  }
  // epilogue 1: relu + bf16 -> wave-local LDS slab
  unsigned short* sAw = sA[w];
#pragma unroll
  for (int nt = 0; nt < 8; ++nt) {
    int col = nt * 16 + c;
    float b = bias1[col];
#pragma unroll
    for (int rr = 0; rr < 4; ++rr) {
      float v = fmaxf(acc[nt][rr] + b, 0.f);
      sAw[(hi * 4 + rr) * 136 + col] = f2bf(v);
    }
  }
  __syncthreads();  // sA ready; all waves done reading sB1
  // stage B2 into LDS
  {
    const short8* src = (const short8*)P2;
    short8* dst = (short8*)sB;
#pragma unroll
    for (int i = 0; i < 8; ++i) dst[tid + i * 256] = src[tid + i * 256];
  }
  __syncthreads();

  // stage 2
#pragma unroll
  for (int nt = 0; nt < 8; ++nt) acc[nt] = (f32x4){0.f, 0.f, 0.f, 0.f};
#pragma unroll
  for (int ks = 0; ks < 4; ++ks) {
    short8 af = *(const short8*)&sAw[c * 136 + ks * 32 + koff];
#pragma unroll
    for (int nt = 0; nt < 8; ++nt)
      acc[nt] = __builtin_amdgcn_mfma_f32_16x16x32_bf16(af, sBv[ks * 512 + nt * 64 + lane],
                                                        acc[nt], 0, 0, 0);
  }
  // epilogue 2: relu + fp32 write + fused BN stats
#pragma unroll
  for (int nt = 0; nt < 8; ++nt) {
    int col = nt * 16 + c;
    float b = bias2[col];
    float s = 0.f, q = 0.f;
#pragma unroll
    for (int rr = 0; rr < 4; ++rr) {
      int row = rb + hi * 4 + rr;
      if (row < M) {
        float v = fmaxf(acc[nt][rr] + b, 0.f);
        H[(size_t)row * HID + col] = v;
        s += v;
        q += v * v;
      }
    }
    s += __shfl_xor(s, 16, 64);
    q += __shfl_xor(q, 16, 64);
    s += __shfl_xor(s, 32, 64);
    q += __shfl_xor(q, 32, 64);
    if (hi == 0) {
      atomicAdd(&sSum[col], s);
      atomicAdd(&sSq[col], q);
    }
  }
  __syncthreads();
  if (tid < 128) {
    unsafeAtomicAdd(&gsum[tid], sSum[tid]);
    unsafeAtomicAdd(&gsq[tid], sSq[tid]);
  }
}

// ---------------- MFMA JK GEMM: t2 = relu(concat(hb0..hb3) @ lin1_W + b), fp32 out ----
// lin1_W staged in LDS one 32KB layer-slab at a time.
__global__ __launch_bounds__(256, 3) void mjkgemm_k(const unsigned short* __restrict__ H0,
                                                    const unsigned short* __restrict__ H1,
                                                    const unsigned short* __restrict__ H2,
                                                    const unsigned short* __restrict__ H3,
                                                    const unsigned short* __restrict__ P,
                                                    const float* __restrict__ bias,
                                                    float* __restrict__ C, int M) {
  __shared__ unsigned short sB[16384];
  int tid = threadIdx.x;
  int lane = tid & 63, w = tid >> 6;
  int rb = blockIdx.x * 64 + w * 16;
  int r = rb + (lane & 15);
  if (r > M - 1) r = M - 1;
  int koff = (lane >> 4) * 8;
  f32x4 acc[8];
#pragma unroll
  for (int nt = 0; nt < 8; ++nt) acc[nt] = (f32x4){0.f, 0.f, 0.f, 0.f};
  const unsigned short* Hs[4] = {H0, H1, H2, H3};
  const short8* sBv = (const short8*)sB;
  for (int l = 0; l < 4; ++l) {
    __syncthreads();  // prev-iter reads complete before overwrite
    {
      const short8* src = (const short8*)(P + l * 16384);
      short8* dst = (short8*)sB;
#pragma unroll
      for (int i = 0; i < 8; ++i) dst[tid + i * 256] = src[tid + i * 256];
    }
    // hoist this layer's A loads
    short8 a_[4];
    const unsigned short* Ar = Hs[l] + (size_t)r * HID + koff;
#pragma unroll
    for (int ks = 0; ks < 4; ++ks) a_[ks] = *(const short8*)(Ar + ks * 32);
    __syncthreads();
#pragma unroll
    for (int ks = 0; ks < 4; ++ks) {
#pragma unroll
      for (int nt = 0; nt < 8; ++nt)
        acc[nt] = __builtin_amdgcn_mfma_f32_16x16x32_bf16(a_[ks], sBv[ks * 512 + nt * 64 + lane],
                                                          acc[nt], 0, 0, 0);
    }
  }
  int hi = lane >> 4, c = lane & 15;
#pragma unroll
  for (int nt = 0; nt < 8; ++nt) {
    int col = nt * 16 + c;
    float b = bias[col];
#pragma unroll
    for (int rr = 0; rr < 4; ++rr) {
      int row = rb + hi * 4 + rr;
      if (row < M) {
        float v = fmaxf(acc[nt][rr] + b, 0.f);
        C[(size_t)row * HID + col] = v;
      }
    }
  }
}

// ---------------- BatchNorm normalize: fp32 h -> bf16 hb ----------------
__global__ void bn_norm_k(const float* __restrict__ H, unsigned short* __restrict__ HB,
                          const float* __restrict__ stats, const float* __restrict__ gamma,
                          const float* __restrict__ beta) {
  int i = blockIdx.x * 256 + threadIdx.x;
  if (i >= NNODES * 32) return;
  int c4 = i & 31;
  float4 v = ((const float4*)H)[i];
  float4 sm = ((const float4*)stats)[c4];
  float4 sq = ((const float4*)(stats + 128))[c4];
  float4 g = ((const float4*)gamma)[c4];
  float4 bt = ((const float4*)beta)[c4];
  const float invN = 1.0f / (float)NNODES;
  float m, var, inv;
  ushort4 o;
  m = sm.x * invN; var = sq.x * invN - m * m; inv = rsqrtf(var + BN_EPS);
  o.x = f2bf((v.x - m) * inv * g.x + bt.x);
  m = sm.y * invN; var = sq.y * invN - m * m; inv = rsqrtf(var + BN_EPS);
  o.y = f2bf((v.y - m) * inv * g.y + bt.y);
  m = sm.z * invN; var = sq.z * invN - m * m; inv = rsqrtf(var + BN_EPS);
  o.z = f2bf((v.z - m) * inv * g.z + bt.z);
  m = sm.w * invN; var = sq.w * invN - m * m; inv = rsqrtf(var + BN_EPS);
  o.w = f2bf((v.w - m) * inv * g.w + bt.w);
  ((ushort4*)HB)[i] = o;
}

// ---------------- head: out[M,8] = t2[M,128] @ W[128,8] + b ----------------
__global__ void head_k(const float* __restrict__ O1, const float* __restrict__ W,
                       const float* __restrict__ b, float* __restrict__ out, int M) {
  __shared__ float sW[HID * NOUT];
  int tid = threadIdx.x;
#pragma unroll
  for (int i = 0; i < 4; ++i) sW[tid + i * 256] = W[tid + i * 256];
  __syncthreads();
  int row = blockIdx.x * 256 + tid;
  if (row >= M) return;
  float acc[NOUT];
#pragma unroll
  for (int j = 0; j < NOUT; ++j) acc[j] = b[j];
  const float* Ar = O1 + (size_t)row * HID;
  for (int k = 0; k < HID; k += 4) {
    float4 a = *(const float4*)(Ar + k);
#pragma unroll
    for (int kk = 0; kk < 4; ++kk) {
      float av = ((const float*)&a)[kk];
#pragma unroll
      for (int j = 0; j < NOUT; ++j) acc[j] += av * sW[(k + kk) * NOUT + j];
    }
  }
#pragma unroll
  for (int j = 0; j < NOUT; ++j) out[(size_t)row * NOUT + j] = acc[j];
}

// ---------------- launch ----------------

extern "C" void kernel_launch(void* const* d_in, const int* in_sizes, int n_in,
                              void* d_out, int out_size, void* d_ws, size_t ws_size,
                              hipStream_t stream) {
  const float* x     = (const float*)d_in[0];
  const int*   ei    = (const int*)d_in[1];
  const float* W1    = (const float*)d_in[2];
  const float* b1    = (const float*)d_in[3];
  const float* W2    = (const float*)d_in[4];
  const float* b2    = (const float*)d_in[5];
  const float* gamma = (const float*)d_in[6];
  const float* beta  = (const float*)d_in[7];
  const float* l1W   = (const float*)d_in[8];
  const float* l1b   = (const float*)d_in[9];
  const float* l2W   = (const float*)d_in[10];
  const float* l2b   = (const float*)d_in[11];

  float* ws = (float*)d_ws;
  const size_t NB = (size_t)NNODES * HID;    // 6.4e6 elements
  const size_t NBH = NB / 2;                 // bf16 buffer size in float units
  float* h = ws;                             // fp32 pre-BN (reused each layer)
  float* t2 = ws + NB;                       // fp32 jk output
  unsigned short* xb = (unsigned short*)(ws + 2 * NB);            // bf16 x
  unsigned short* tmp = (unsigned short*)(ws + 2 * NB + NBH);     // bf16 agg out
  unsigned short* hb[4];
  for (int l = 0; l < 4; ++l)
    hb[l] = (unsigned short*)(ws + 2 * NB + (2 + l) * NBH);  // bf16 post-BN
  float* stats = ws + 2 * NB + 6 * NBH;
  int* flag = (int*)(stats + 1024);
  int* deg = flag + 4;
  int* off = deg + (NNODES + 1);
  int* cursor = off + (NNODES + 1);
  int* bsum = cursor + (NNODES + 1);
  int* boff = bsum + 256;
  int* srcs = boff + 260;
  size_t pofs = 2 * NB + 6 * NBH + 1024 + 4 + 3 * (size_t)(NNODES + 1) + 256 + 260 + NEDGES;
  pofs = (pofs + 3) & ~(size_t)3;  // 16B align
  unsigned short* P = (unsigned short*)(ws + pofs);
  // P: W1 layer l at l*16384; W2 layer l at 65536 + l*16384; lin1 at 131072.

  detect64_k<<<1, 256, 0, stream>>>(ei, flag);
  zero_stats_k<<<1, 256, 0, stream>>>(stats);
  zero_deg_k<<<NBLK, 256, 0, stream>>>(deg);
  hist_k<<<2344, 256, 0, stream>>>(ei, flag, deg);
  blocksum_k<<<NBLK, 256, 0, stream>>>(deg, bsum);
  scanb_k<<<1, 256, 0, stream>>>(bsum, boff);
  writeoff_k<<<NBLK, 256, 0, stream>>>(deg, boff, off, cursor);
  fill_k<<<2344, 256, 0, stream>>>(ei, flag, cursor, srcs);
  packW_k<<<96, 256, 0, stream>>>(W1, W2, l1W, P);
  cvt_bf_k<<<6250, 256, 0, stream>>>(x, xb, NNODES * 32);

  const unsigned short* hin = xb;
  for (int l = 0; l < NLAYERS; ++l) {
    gather_agg_k<<<6250, 256, 0, stream>>>(hin, off, srcs, tmp);
    mlp_k<<<782, 256, 0, stream>>>(tmp, P + (size_t)l * 16384, b1 + l * HID,
                                   P + 65536 + (size_t)l * 16384, b2 + l * HID, h, NNODES,
                                   stats + l * 256, stats + l * 256 + 128);
    bn_norm_k<<<6250, 256, 0, stream>>>(h, hb[l], stats + l * 256, gamma + l * HID,
                                        beta + l * HID);
    hin = hb[l];
  }
  mjkgemm_k<<<782, 256, 0, stream>>>(hb[0], hb[1], hb[2], hb[3], P + 131072, l1b, t2, NNODES);
  head_k<<<196, 256, 0, stream>>>(t2, l2W, l2b, (float*)d_out, NNODES);
}

// Round 8
// 390.332 us; speedup vs baseline: 1.0892x; 1.0892x over previous
//
#include <hip/hip_runtime.h>

#define NNODES 50000
#define NEDGES 600000
#define HID 128
#define NLAYERS 4
#define NOUT 8
#define BN_EPS 1e-5f
#define NBLK 196    // ceil(NNODES/256)
#define NPBLK 1563  // ceil(NNODES/32) — 32-row MLP blocks

typedef short short8 __attribute__((ext_vector_type(8)));
typedef float f32x4 __attribute__((ext_vector_type(4)));

__device__ inline unsigned short f2bf(float f) {
  unsigned u = __float_as_uint(f);
  unsigned r = ((u >> 16) & 1u) + 0x7fffu;
  return (unsigned short)((u + r) >> 16);
}
__device__ inline float bflo(unsigned w) { return __uint_as_float(w << 16); }
__device__ inline float bfhi(unsigned w) { return __uint_as_float(w & 0xffff0000u); }

// ---------------- utility kernels ----------------

// Detect whether edge_index arrived as int64 (odd int32 words all zero) or int32.
__global__ void detect64_k(const int* __restrict__ ei, int* __restrict__ flag) {
  __shared__ int anynz;
  if (threadIdx.x == 0) anynz = 0;
  __syncthreads();
  int acc = 0;
  for (int i = threadIdx.x; i < 4096; i += 256) {
    int p = i * 146;
    acc |= ei[2 * p + 1];
  }
  if (acc != 0) anynz = 1;
  __syncthreads();
  if (threadIdx.x == 0) *flag = (anynz == 0) ? 1 : 0;  // 1 => int64 layout
}

// fp32 -> bf16 convert (for the input x gather table)
__global__ void cvt_bf_k(const float* __restrict__ src, unsigned short* __restrict__ dst,
                         int n4) {
  int i = blockIdx.x * 256 + threadIdx.x;
  if (i >= n4) return;
  float4 v = ((const float4*)src)[i];
  ushort4 o;
  o.x = f2bf(v.x);
  o.y = f2bf(v.y);
  o.z = f2bf(v.z);
  o.w = f2bf(v.w);
  ((ushort4*)dst)[i] = o;
}

// ---------------- CSR build ----------------

__global__ void zero_deg_k(int* __restrict__ deg) {
  int i = blockIdx.x * 256 + threadIdx.x;
  if (i < NNODES + 1) deg[i] = 0;
}

__global__ void hist_k(const int* __restrict__ ei, const int* __restrict__ flag,
                       int* __restrict__ deg) {
  int e = blockIdx.x * 256 + threadIdx.x;
  if (e >= NEDGES) return;
  int d = (*flag) ? ei[2 * NEDGES + 2 * e] : ei[NEDGES + e];
  atomicAdd(&deg[d], 1);
}

// Parallel scan, phase A: per-block (256-chunk) sums.
__global__ void blocksum_k(const int* __restrict__ deg, int* __restrict__ bsum) {
  int t = threadIdx.x;
  int i = blockIdx.x * 256 + t;
  __shared__ int sh[256];
  sh[t] = (i < NNODES) ? deg[i] : 0;
  __syncthreads();
  for (int s = 128; s > 0; s >>= 1) {
    if (t < s) sh[t] += sh[t + s];
    __syncthreads();
  }
  if (t == 0) bsum[blockIdx.x] = sh[0];
}

// Phase B: single-block exclusive scan of the NBLK block sums.
__global__ void scanb_k(const int* __restrict__ bsum, int* __restrict__ boff) {
  __shared__ int sh[256];
  int t = threadIdx.x;
  sh[t] = (t < NBLK) ? bsum[t] : 0;
  __syncthreads();
  for (int d = 1; d < 256; d <<= 1) {
    int v = (t >= d) ? sh[t - d] : 0;
    __syncthreads();
    sh[t] += v;
    __syncthreads();
  }
  if (t < NBLK) boff[t] = (t == 0) ? 0 : sh[t - 1];
}

// Phase C: per-block exclusive scan + block offset -> off/cursor.
__global__ void writeoff_k(const int* __restrict__ deg, const int* __restrict__ boff,
                           int* __restrict__ off, int* __restrict__ cursor) {
  int t = threadIdx.x;
  int i = blockIdx.x * 256 + t;
  __shared__ int sh[256];
  int v = (i < NNODES) ? deg[i] : 0;
  sh[t] = v;
  __syncthreads();
  for (int d = 1; d < 256; d <<= 1) {
    int u = (t >= d) ? sh[t - d] : 0;
    __syncthreads();
    sh[t] += u;
    __syncthreads();
  }
  int excl = boff[blockIdx.x] + sh[t] - v;
  if (i < NNODES) {
    off[i] = excl;
    cursor[i] = excl;
  }
  if (i == NNODES - 1) off[NNODES] = excl + v;
}

__global__ void fill_k(const int* __restrict__ ei, const int* __restrict__ flag,
                       int* __restrict__ cursor, int* __restrict__ srcs) {
  int e = blockIdx.x * 256 + threadIdx.x;
  if (e >= NEDGES) return;
  int s, d;
  if (*flag) {
    s = ei[2 * e];
    d = ei[2 * NEDGES + 2 * e];
  } else {
    s = ei[e];
    d = ei[NEDGES + e];
  }
  int pos = atomicAdd(&cursor[d], 1);
  srcs[pos] = s;
}

// ---------------- fused gather-aggregate (bf16 table -> bf16 out) ----------------
__global__ void gather_agg_k(const unsigned short* __restrict__ X,
                             const int* __restrict__ off, const int* __restrict__ srcs,
                             unsigned short* __restrict__ T) {
  int gid = blockIdx.x * 256 + threadIdx.x;
  int node = gid >> 5;
  if (node >= NNODES) return;
  int lane = gid & 31;
  int a = off[node], b = off[node + 1];
  const uint2* Xv = (const uint2*)X;
  uint2 w = Xv[(size_t)node * 32 + lane];
  float a0 = bflo(w.x), a1 = bfhi(w.x), a2 = bflo(w.y), a3 = bfhi(w.y);
  for (int base = a; base < b; base += 32) {
    int cnt = b - base;
    if (cnt > 32) cnt = 32;
    int idx = (lane < cnt) ? srcs[base + lane] : 0;
#pragma unroll 8
    for (int i = 0; i < cnt; ++i) {
      int s = __shfl(idx, i, 32);
      uint2 v = Xv[(size_t)s * 32 + lane];
      a0 += bflo(v.x);
      a1 += bfhi(v.x);
      a2 += bflo(v.y);
      a3 += bfhi(v.y);
    }
  }
  uint2 o;
  o.x = (unsigned)f2bf(a0) | ((unsigned)f2bf(a1) << 16);
  o.y = (unsigned)f2bf(a2) | ((unsigned)f2bf(a3) << 16);
  ((uint2*)T)[(size_t)node * 32 + lane] = o;
}

// ---------------- weight pre-pack into MFMA B-fragment layout ----------------
__global__ void packW_k(const float* __restrict__ W1, const float* __restrict__ W2,
                        const float* __restrict__ L1, unsigned short* __restrict__ P) {
  int t = blockIdx.x * 256 + threadIdx.x;
  if (t >= 48 * 512) return;
  int gk = t >> 9;
  int nt = (t >> 6) & 7;
  int lane = t & 63;
  const float* src;
  int kbase;
  if (gk < 16) {
    src = W1 + (gk >> 2) * 16384;
    kbase = (gk & 3) * 32;
  } else if (gk < 32) {
    src = W2 + ((gk - 16) >> 2) * 16384;
    kbase = ((gk - 16) & 3) * 32;
  } else {
    src = L1;
    kbase = (gk - 32) * 32;
  }
  int n = nt * 16 + (lane & 15);
  int k0 = kbase + (lane >> 4) * 8;
  unsigned short* dst = P + (size_t)t * 8;
#pragma unroll
  for (int j = 0; j < 8; ++j) dst[j] = f2bf(src[(size_t)(k0 + j) * HID + n]);
}

// ---------------- fused MLP: H = relu(relu(A@W1+b1)@W2+b2); stats -> pstats ----------
// 2 waves/block, 32 rows/block, grid NPBLK. B-fragments from global (L2-resident),
// double-buffered in registers. BN stat partials stored per block (no global atomics).
__global__ __launch_bounds__(128) void mlp_k(const unsigned short* __restrict__ A,
                                             const unsigned short* __restrict__ P1,
                                             const float* __restrict__ bias1,
                                             const unsigned short* __restrict__ P2,
                                             const float* __restrict__ bias2,
                                             float* __restrict__ H, int M,
                                             float* __restrict__ pstats) {
  __shared__ unsigned short sA[2][16 * 136];
  __shared__ float sSum[128], sSq[128];
  int tid = threadIdx.x;
  if (tid < 128) {
    sSum[tid] = 0.f;
    sSq[tid] = 0.f;
  }
  int lane = tid & 63, w = tid >> 6;
  int rb = blockIdx.x * 32 + w * 16;
  int r = rb + (lane & 15);
  if (r > M - 1) r = M - 1;
  int hi = lane >> 4, c = lane & 15;
  int koff = hi * 8;

  // hoisted A-row loads
  short8 a_[4];
  const unsigned short* Ar = A + (size_t)r * HID + koff;
#pragma unroll
  for (int ks = 0; ks < 4; ++ks) a_[ks] = *(const short8*)(Ar + ks * 32);

  const short8* Bp1 = (const short8*)P1;
  f32x4 acc[8];
#pragma unroll
  for (int nt = 0; nt < 8; ++nt) acc[nt] = (f32x4){0.f, 0.f, 0.f, 0.f};
  short8 bcur[8], bnxt[8];
#pragma unroll
  for (int nt = 0; nt < 8; ++nt) bcur[nt] = Bp1[nt * 64 + lane];
#pragma unroll
  for (int ks = 0; ks < 4; ++ks) {
    if (ks < 3) {
#pragma unroll
      for (int nt = 0; nt < 8; ++nt) bnxt[nt] = Bp1[(ks + 1) * 512 + nt * 64 + lane];
    }
#pragma unroll
    for (int nt = 0; nt < 8; ++nt)
      acc[nt] = __builtin_amdgcn_mfma_f32_16x16x32_bf16(a_[ks], bcur[nt], acc[nt], 0, 0, 0);
    if (ks < 3) {
#pragma unroll
      for (int nt = 0; nt < 8; ++nt) bcur[nt] = bnxt[nt];
    }
  }
  // epilogue 1: relu + bf16 -> wave-local LDS slab
  unsigned short* sAw = sA[w];
#pragma unroll
  for (int nt = 0; nt < 8; ++nt) {
    int col = nt * 16 + c;
    float b = bias1[col];
#pragma unroll
    for (int rr = 0; rr < 4; ++rr) {
      float v = fmaxf(acc[nt][rr] + b, 0.f);
      sAw[(hi * 4 + rr) * 136 + col] = f2bf(v);
    }
  }
  __syncthreads();

  // stage 2
#pragma unroll
  for (int nt = 0; nt < 8; ++nt) acc[nt] = (f32x4){0.f, 0.f, 0.f, 0.f};
  const short8* Bp2 = (const short8*)P2;
#pragma unroll
  for (int nt = 0; nt < 8; ++nt) bcur[nt] = Bp2[nt * 64 + lane];
#pragma unroll
  for (int ks = 0; ks < 4; ++ks) {
    short8 af = *(const short8*)&sAw[c * 136 + ks * 32 + koff];
    if (ks < 3) {
#pragma unroll
      for (int nt = 0; nt < 8; ++nt) bnxt[nt] = Bp2[(ks + 1) * 512 + nt * 64 + lane];
    }
#pragma unroll
    for (int nt = 0; nt < 8; ++nt)
      acc[nt] = __builtin_amdgcn_mfma_f32_16x16x32_bf16(af, bcur[nt], acc[nt], 0, 0, 0);
    if (ks < 3) {
#pragma unroll
      for (int nt = 0; nt < 8; ++nt) bcur[nt] = bnxt[nt];
    }
  }
  // epilogue 2: relu + fp32 write + BN stat partials
#pragma unroll
  for (int nt = 0; nt < 8; ++nt) {
    int col = nt * 16 + c;
    float b = bias2[col];
    float s = 0.f, q = 0.f;
#pragma unroll
    for (int rr = 0; rr < 4; ++rr) {
      int row = rb + hi * 4 + rr;
      if (row < M) {
        float v = fmaxf(acc[nt][rr] + b, 0.f);
        H[(size_t)row * HID + col] = v;
        s += v;
        q += v * v;
      }
    }
    s += __shfl_xor(s, 16, 64);
    q += __shfl_xor(q, 16, 64);
    s += __shfl_xor(s, 32, 64);
    q += __shfl_xor(q, 32, 64);
    if (hi == 0) {
      atomicAdd(&sSum[col], s);  // LDS atomics, 2 waves only
      atomicAdd(&sSq[col], q);
    }
  }
  __syncthreads();
  if (tid < 128) {
    float* dst = pstats + (size_t)blockIdx.x * 256;
    dst[tid] = sSum[tid];
    dst[128 + tid] = sSq[tid];
  }
}

// ---------------- stats finalize: stats[j] = sum_b pstats[b][j] ----------------
__global__ void reduce_stats_k(const float* __restrict__ pstats, float* __restrict__ stats) {
  __shared__ float sh[256];
  int j = blockIdx.x;  // 0..255 channel-slot
  int t = threadIdx.x;
  float acc = 0.f;
  for (int b = t; b < NPBLK; b += 256) acc += pstats[(size_t)b * 256 + j];
  sh[t] = acc;
  __syncthreads();
  for (int s = 128; s > 0; s >>= 1) {
    if (t < s) sh[t] += sh[t + s];
    __syncthreads();
  }
  if (t == 0) stats[j] = sh[0];
}

// ---------------- MFMA JK GEMM: t2 = relu(concat(hb0..hb3) @ lin1_W + b), fp32 out ----
// 2 waves/block, 32 rows/block, B from global with register double-buffer.
__global__ __launch_bounds__(128) void mjkgemm_k(const unsigned short* __restrict__ H0,
                                                 const unsigned short* __restrict__ H1,
                                                 const unsigned short* __restrict__ H2,
                                                 const unsigned short* __restrict__ H3,
                                                 const unsigned short* __restrict__ P,
                                                 const float* __restrict__ bias,
                                                 float* __restrict__ C, int M) {
  int tid = threadIdx.x;
  int lane = tid & 63, w = tid >> 6;
  int rb = blockIdx.x * 32 + w * 16;
  int r = rb + (lane & 15);
  if (r > M - 1) r = M - 1;
  int koff = (lane >> 4) * 8;
  f32x4 acc[8];
#pragma unroll
  for (int nt = 0; nt < 8; ++nt) acc[nt] = (f32x4){0.f, 0.f, 0.f, 0.f};
  const unsigned short* Hs[4] = {H0, H1, H2, H3};
  short8 bcur[8], bnxt[8];
  for (int l = 0; l < 4; ++l) {
    const short8* Bp = (const short8*)(P + l * 16384);
    short8 a_[4];
    const unsigned short* Ar = Hs[l] + (size_t)r * HID + koff;
#pragma unroll
    for (int ks = 0; ks < 4; ++ks) a_[ks] = *(const short8*)(Ar + ks * 32);
#pragma unroll
    for (int nt = 0; nt < 8; ++nt) bcur[nt] = Bp[nt * 64 + lane];
#pragma unroll
    for (int ks = 0; ks < 4; ++ks) {
      if (ks < 3) {
#pragma unroll
        for (int nt = 0; nt < 8; ++nt) bnxt[nt] = Bp[(ks + 1) * 512 + nt * 64 + lane];
      }
#pragma unroll
      for (int nt = 0; nt < 8; ++nt)
        acc[nt] = __builtin_amdgcn_mfma_f32_16x16x32_bf16(a_[ks], bcur[nt], acc[nt], 0, 0, 0);
      if (ks < 3) {
#pragma unroll
        for (int nt = 0; nt < 8; ++nt) bcur[nt] = bnxt[nt];
      }
    }
  }
  int hi = lane >> 4, c = lane & 15;
#pragma unroll
  for (int nt = 0; nt < 8; ++nt) {
    int col = nt * 16 + c;
    float b = bias[col];
#pragma unroll
    for (int rr = 0; rr < 4; ++rr) {
      int row = rb + hi * 4 + rr;
      if (row < M) {
        float v = fmaxf(acc[nt][rr] + b, 0.f);
        C[(size_t)row * HID + col] = v;
      }
    }
  }
}

// ---------------- BatchNorm normalize: fp32 h -> bf16 hb ----------------
__global__ void bn_norm_k(const float* __restrict__ H, unsigned short* __restrict__ HB,
                          const float* __restrict__ stats, const float* __restrict__ gamma,
                          const float* __restrict__ beta) {
  int i = blockIdx.x * 256 + threadIdx.x;
  if (i >= NNODES * 32) return;
  int c4 = i & 31;
  float4 v = ((const float4*)H)[i];
  float4 sm = ((const float4*)stats)[c4];
  float4 sq = ((const float4*)(stats + 128))[c4];
  float4 g = ((const float4*)gamma)[c4];
  float4 bt = ((const float4*)beta)[c4];
  const float invN = 1.0f / (float)NNODES;
  float m, var, inv;
  ushort4 o;
  m = sm.x * invN; var = sq.x * invN - m * m; inv = rsqrtf(var + BN_EPS);
  o.x = f2bf((v.x - m) * inv * g.x + bt.x);
  m = sm.y * invN; var = sq.y * invN - m * m; inv = rsqrtf(var + BN_EPS);
  o.y = f2bf((v.y - m) * inv * g.y + bt.y);
  m = sm.z * invN; var = sq.z * invN - m * m; inv = rsqrtf(var + BN_EPS);
  o.z = f2bf((v.z - m) * inv * g.z + bt.z);
  m = sm.w * invN; var = sq.w * invN - m * m; inv = rsqrtf(var + BN_EPS);
  o.w = f2bf((v.w - m) * inv * g.w + bt.w);
  ((ushort4*)HB)[i] = o;
}

// ---------------- head: out[M,8] = t2[M,128] @ W[128,8] + b ----------------
__global__ void head_k(const float* __restrict__ O1, const float* __restrict__ W,
                       const float* __restrict__ b, float* __restrict__ out, int M) {
  __shared__ float sW[HID * NOUT];
  int tid = threadIdx.x;
#pragma unroll
  for (int i = 0; i < 4; ++i) sW[tid + i * 256] = W[tid + i * 256];
  __syncthreads();
  int row = blockIdx.x * 256 + tid;
  if (row >= M) return;
  float acc[NOUT];
#pragma unroll
  for (int j = 0; j < NOUT; ++j) acc[j] = b[j];
  const float* Ar = O1 + (size_t)row * HID;
  for (int k = 0; k < HID; k += 4) {
    float4 a = *(const float4*)(Ar + k);
#pragma unroll
    for (int kk = 0; kk < 4; ++kk) {
      float av = ((const float*)&a)[kk];
#pragma unroll
      for (int j = 0; j < NOUT; ++j) acc[j] += av * sW[(k + kk) * NOUT + j];
    }
  }
#pragma unroll
  for (int j = 0; j < NOUT; ++j) out[(size_t)row * NOUT + j] = acc[j];
}

// ---------------- launch ----------------

extern "C" void kernel_launch(void* const* d_in, const int* in_sizes, int n_in,
                              void* d_out, int out_size, void* d_ws, size_t ws_size,
                              hipStream_t stream) {
  const float* x     = (const float*)d_in[0];
  const int*   ei    = (const int*)d_in[1];
  const float* W1    = (const float*)d_in[2];
  const float* b1    = (const float*)d_in[3];
  const float* W2    = (const float*)d_in[4];
  const float* b2    = (const float*)d_in[5];
  const float* gamma = (const float*)d_in[6];
  const float* beta  = (const float*)d_in[7];
  const float* l1W   = (const float*)d_in[8];
  const float* l1b   = (const float*)d_in[9];
  const float* l2W   = (const float*)d_in[10];
  const float* l2b   = (const float*)d_in[11];

  float* ws = (float*)d_ws;
  const size_t NB = (size_t)NNODES * HID;    // 6.4e6 elements
  const size_t NBH = NB / 2;                 // bf16 buffer size in float units
  float* h = ws;                             // fp32 pre-BN (reused each layer)
  float* t2 = ws + NB;                       // fp32 jk output
  unsigned short* xb = (unsigned short*)(ws + 2 * NB);            // bf16 x
  unsigned short* tmp = (unsigned short*)(ws + 2 * NB + NBH);     // bf16 agg out
  unsigned short* hb[4];
  for (int l = 0; l < 4; ++l)
    hb[l] = (unsigned short*)(ws + 2 * NB + (2 + l) * NBH);  // bf16 post-BN
  float* stats = ws + 2 * NB + 6 * NBH;
  int* flag = (int*)(stats + 1024);
  int* deg = flag + 4;
  int* off = deg + (NNODES + 1);
  int* cursor = off + (NNODES + 1);
  int* bsum = cursor + (NNODES + 1);
  int* boff = bsum + 256;
  int* srcs = boff + 260;
  size_t pofs = 2 * NB + 6 * NBH + 1024 + 4 + 3 * (size_t)(NNODES + 1) + 256 + 260 + NEDGES;
  pofs = (pofs + 3) & ~(size_t)3;  // 16B align
  unsigned short* P = (unsigned short*)(ws + pofs);
  // P: W1 layer l at l*16384; W2 layer l at 65536 + l*16384; lin1 at 131072.
  float* pstats = ws + pofs + 98304;  // NPBLK x 256 partial stats

  detect64_k<<<1, 256, 0, stream>>>(ei, flag);
  zero_deg_k<<<NBLK, 256, 0, stream>>>(deg);
  hist_k<<<2344, 256, 0, stream>>>(ei, flag, deg);
  blocksum_k<<<NBLK, 256, 0, stream>>>(deg, bsum);
  scanb_k<<<1, 256, 0, stream>>>(bsum, boff);
  writeoff_k<<<NBLK, 256, 0, stream>>>(deg, boff, off, cursor);
  fill_k<<<2344, 256, 0, stream>>>(ei, flag, cursor, srcs);
  packW_k<<<96, 256, 0, stream>>>(W1, W2, l1W, P);
  cvt_bf_k<<<6250, 256, 0, stream>>>(x, xb, NNODES * 32);

  const unsigned short* hin = xb;
  for (int l = 0; l < NLAYERS; ++l) {
    gather_agg_k<<<6250, 256, 0, stream>>>(hin, off, srcs, tmp);
    mlp_k<<<NPBLK, 128, 0, stream>>>(tmp, P + (size_t)l * 16384, b1 + l * HID,
                                     P + 65536 + (size_t)l * 16384, b2 + l * HID, h, NNODES,
                                     pstats);
    reduce_stats_k<<<256, 256, 0, stream>>>(pstats, stats + l * 256);
    bn_norm_k<<<6250, 256, 0, stream>>>(h, hb[l], stats + l * 256, gamma + l * HID,
                                        beta + l * HID);
    hin = hb[l];
  }
  mjkgemm_k<<<NPBLK, 128, 0, stream>>>(hb[0], hb[1], hb[2], hb[3], P + 131072, l1b, t2, NNODES);
  head_k<<<196, 256, 0, stream>>>(t2, l2W, l2b, (float*)d_out, NNODES);
}